// Round 4
// baseline (2165.922 us; speedup 1.0000x reference)
//
#include <hip/hip_runtime.h>
#include <cstdint>
#include <cstddef>

#define SS 4096
#define HH 16
#define BH 64   // B*H

typedef unsigned short bfu;

__device__ __forceinline__ float bf2f(bfu u) { return __uint_as_float(((unsigned)u) << 16); }
__device__ __forceinline__ bfu f2bf(float f) {
    unsigned u = __float_as_uint(f);
    return (bfu)((u + 0x7fffu + ((u >> 16) & 1u)) >> 16);
}
union BF8 { uint4 u4; bfu h[8]; };

__device__ __forceinline__ unsigned encf(float x) {
    unsigned u = __float_as_uint(x);
    return (u & 0x80000000u) ? ~u : (u | 0x80000000u);
}
__device__ __forceinline__ float decf(unsigned u) {
    return (u & 0x80000000u) ? __uint_as_float(u & 0x7fffffffu) : __uint_as_float(~u);
}

__global__ void diag_kernel(float* __restrict__ out, float val, int n) {
    int i = blockIdx.x * 256 + threadIdx.x;
    if (i < n) out[i] = val;
}

// ---------------- QKV projection GEMM: X[16384,1024] @ {Wq,Wk,Wv} -> bf16 q,k,v ----------------
__global__ __launch_bounds__(256) void gemm_qkv_kernel(
    const float* __restrict__ X,
    const float* __restrict__ Wq, const float* __restrict__ Wk, const float* __restrict__ Wv,
    const float* __restrict__ bq, const float* __restrict__ bk, const float* __restrict__ bv,
    bfu* __restrict__ q, bfu* __restrict__ k, bfu* __restrict__ v)
{
    __shared__ float As[16][128];   // [k][m]
    __shared__ float Bs[16][128];   // [k][n]
    int tid = threadIdx.x;
    int nt = blockIdx.x;            // 0..23
    int mt = blockIdx.y;            // 0..127
    int row0 = mt * 128;
    int n0g = nt * 128;
    int tsel = n0g >> 10;
    int n0 = n0g & 1023;
    const float* W    = tsel == 0 ? Wq : (tsel == 1 ? Wk : Wv);
    const float* bias = tsel == 0 ? bq : (tsel == 1 ? bk : bv);
    bfu* Out          = tsel == 0 ? q  : (tsel == 1 ? k  : v);
    float scale = tsel == 0 ? 0.125f : 1.0f;

    int tx = tid & 15, ty = tid >> 4;
    float acc[8][8] = {};

    for (int k0 = 0; k0 < 1024; k0 += 16) {
        #pragma unroll
        for (int i2 = 0; i2 < 2; i2++) {
            int idx = tid * 2 + i2;
            int r = idx >> 2, c4 = (idx & 3) * 4;
            float4 a = *reinterpret_cast<const float4*>(&X[(size_t)(row0 + r) * 1024 + k0 + c4]);
            As[c4 + 0][r] = a.x; As[c4 + 1][r] = a.y; As[c4 + 2][r] = a.z; As[c4 + 3][r] = a.w;
        }
        #pragma unroll
        for (int i2 = 0; i2 < 2; i2++) {
            int idx = tid * 2 + i2;
            int r = idx >> 5, c4 = (idx & 31) * 4;
            *reinterpret_cast<float4*>(&Bs[r][c4]) =
                *reinterpret_cast<const float4*>(&W[(size_t)(k0 + r) * 1024 + n0 + c4]);
        }
        __syncthreads();
        #pragma unroll
        for (int kk = 0; kk < 16; kk++) {
            float a[8], b[8];
            #pragma unroll
            for (int i = 0; i < 8; i++) a[i] = As[kk][ty * 8 + i];
            #pragma unroll
            for (int j = 0; j < 8; j++) b[j] = Bs[kk][tx * 8 + j];
            #pragma unroll
            for (int i = 0; i < 8; i++)
                #pragma unroll
                for (int j = 0; j < 8; j++)
                    acc[i][j] += a[i] * b[j];
        }
        __syncthreads();
    }
    int nbase = n0 + tx * 8;
    int h = nbase >> 6, dh0 = nbase & 63;
    #pragma unroll
    for (int i = 0; i < 8; i++) {
        int row = row0 + ty * 8 + i;
        int b = row >> 12, s = row & 4095;
        BF8 pk;
        #pragma unroll
        for (int j = 0; j < 8; j++)
            pk.h[j] = f2bf((acc[i][j] + bias[nbase + j]) * scale);
        *reinterpret_cast<uint4*>(&Out[(((size_t)(b * HH + h)) * SS + s) * 64 + dh0]) = pk.u4;
    }
}

// ---------------- coarsen (mean of adjacent row pairs), q/k/v fused, bf16 ----------------
__global__ void coarsen3_kernel(const bfu* __restrict__ qi, const bfu* __restrict__ ki,
                                const bfu* __restrict__ vi,
                                bfu* __restrict__ qo, bfu* __restrict__ ko,
                                bfu* __restrict__ vo, int n4)   // n4 = 8-elem chunks per tensor
{
    int idx = blockIdx.x * 256 + threadIdx.x;
    if (idx >= 3 * n4) return;
    int sel = idx / n4;
    int e = idx - sel * n4;
    const bfu* in = sel == 0 ? qi : (sel == 1 ? ki : vi);
    bfu* out      = sel == 0 ? qo : (sel == 1 ? ko : vo);
    int R = e >> 3, c = e & 7;
    BF8 a, b, o;
    a.u4 = reinterpret_cast<const uint4*>(in)[(size_t)(2 * R) * 8 + c];
    b.u4 = reinterpret_cast<const uint4*>(in)[(size_t)(2 * R + 1) * 8 + c];
    #pragma unroll
    for (int t = 0; t < 8; t++)
        o.h[t] = f2bf(0.5f * (bf2f(a.h[t]) + bf2f(b.h[t])));
    reinterpret_cast<uint4*>(out)[e] = o.u4;
}

// ---------------- level-0 similarity (diagonal 32x32 blocks) ----------------
__global__ __launch_bounds__(256) void sim0_kernel(
    const bfu* __restrict__ q, const bfu* __restrict__ k,
    const float* __restrict__ rpb0, float* __restrict__ sim0, unsigned* __restrict__ m_enc)
{
    int bid = blockIdx.x;          // bh*128 + blk
    int blk = bid & 127, bh = bid >> 7;
    int h = bh & 15;
    const bfu* qb = q + ((size_t)bh * SS + blk * 32) * 64;
    const bfu* kb = k + ((size_t)bh * SS + blk * 32) * 64;
    __shared__ float qs[32][65], ks[32][65];
    int tid = threadIdx.x;
    {
        int r = tid >> 3, c8 = (tid & 7) * 8;
        BF8 a; a.u4 = *reinterpret_cast<const uint4*>(qb + (size_t)r * 64 + c8);
        BF8 b; b.u4 = *reinterpret_cast<const uint4*>(kb + (size_t)r * 64 + c8);
        #pragma unroll
        for (int t = 0; t < 8; t++) { qs[r][c8 + t] = bf2f(a.h[t]); ks[r][c8 + t] = bf2f(b.h[t]); }
    }
    __syncthreads();
    int j = tid & 31, i4 = tid >> 5;
    float acc[4] = {0.f, 0.f, 0.f, 0.f};
    for (int d = 0; d < 64; d++) {
        float kv = ks[j][d];
        #pragma unroll
        for (int ii = 0; ii < 4; ii++) acc[ii] += qs[i4 * 4 + ii][d] * kv;
    }
    float lmax = -1e30f;
    float* so = sim0 + (size_t)bid * 1024;
    #pragma unroll
    for (int ii = 0; ii < 4; ii++) {
        int i = i4 * 4 + ii;
        float sv = acc[ii] + rpb0[((j - i) + 63) * 16 + h];
        so[i * 32 + j] = sv;
        lmax = fmaxf(lmax, sv);
    }
    for (int off = 32; off > 0; off >>= 1) lmax = fmaxf(lmax, __shfl_down(lmax, off));
    __shared__ float wm[4];
    if ((tid & 63) == 0) wm[tid >> 6] = lmax;
    __syncthreads();
    if (tid == 0) {
        float m2 = fmaxf(fmaxf(wm[0], wm[1]), fmaxf(wm[2], wm[3]));
        atomicMax(&m_enc[bh], encf(m2));
    }
}

// ---------------- level-l sibling cross similarities ----------------
__global__ __launch_bounds__(256) void simL_kernel(
    const bfu* __restrict__ qc, const bfu* __restrict__ kc,
    const float* __restrict__ rpbl, float* __restrict__ simr, float* __restrict__ siml,
    unsigned* __restrict__ m_enc, int p, int rows)
{
    int bid = blockIdx.x;
    int g2 = bid % (2 * p); int bh = bid / (2 * p);
    int dir = g2 & 1, g = g2 >> 1;   // dir=0: "r" (q even half, k odd); dir=1: "l"
    int h = bh & 15;
    const bfu* qb = qc + ((size_t)bh * rows + g * 64 + dir * 32) * 64;
    const bfu* kb = kc + ((size_t)bh * rows + g * 64 + (1 - dir) * 32) * 64;
    __shared__ float qs[32][65], ks[32][65];
    int tid = threadIdx.x;
    {
        int r = tid >> 3, c8 = (tid & 7) * 8;
        BF8 a; a.u4 = *reinterpret_cast<const uint4*>(qb + (size_t)r * 64 + c8);
        BF8 b; b.u4 = *reinterpret_cast<const uint4*>(kb + (size_t)r * 64 + c8);
        #pragma unroll
        for (int t = 0; t < 8; t++) { qs[r][c8 + t] = bf2f(a.h[t]); ks[r][c8 + t] = bf2f(b.h[t]); }
    }
    __syncthreads();
    int j = tid & 31, i4 = tid >> 5;
    float acc[4] = {0.f, 0.f, 0.f, 0.f};
    for (int d = 0; d < 64; d++) {
        float kv = ks[j][d];
        #pragma unroll
        for (int ii = 0; ii < 4; ii++) acc[ii] += qs[i4 * 4 + ii][d] * kv;
    }
    int boff = dir ? 31 : 95;
    float* so = (dir ? siml : simr) + ((size_t)(bh * p + g)) * 1024;
    float lmax = -1e30f;
    #pragma unroll
    for (int ii = 0; ii < 4; ii++) {
        int i = i4 * 4 + ii;
        float sv = acc[ii] + rpbl[((j - i) + boff) * 16 + h];
        so[i * 32 + j] = sv;
        lmax = fmaxf(lmax, sv);
    }
    for (int off = 32; off > 0; off >>= 1) lmax = fmaxf(lmax, __shfl_down(lmax, off));
    __shared__ float wm[4];
    if ((tid & 63) == 0) wm[tid >> 6] = lmax;
    __syncthreads();
    if (tid == 0) {
        float m2 = fmaxf(fmaxf(wm[0], wm[1]), fmaxf(wm[2], wm[3]));
        atomicMax(&m_enc[bh], encf(m2));
    }
}

__global__ void maxfin_kernel(const unsigned* __restrict__ me, float* __restrict__ mv)
{
    int i = threadIdx.x;
    if (i < 64) mv[i] = 3.0f * decf(me[i]);
}

// ---------------- level-0 PV: y,z initialized here ----------------
__global__ __launch_bounds__(256) void pv0_kernel(
    const float* __restrict__ sim0, const bfu* __restrict__ v,
    const float* __restrict__ mval, float* __restrict__ y, float* __restrict__ z)
{
    int bid = blockIdx.x;
    int blk = bid & 127, bh = bid >> 7;
    float m = mval[bh];
    __shared__ float ps[32][33];
    __shared__ float vs[32][65];
    int tid = threadIdx.x;
    {
        float4 s4 = reinterpret_cast<const float4*>(sim0 + (size_t)bid * 1024)[tid];
        int r = tid >> 3, c4 = (tid & 7) * 4;
        ps[r][c4 + 0] = expf(s4.x - m); ps[r][c4 + 1] = expf(s4.y - m);
        ps[r][c4 + 2] = expf(s4.z - m); ps[r][c4 + 3] = expf(s4.w - m);
    }
    const bfu* vb = v + ((size_t)bh * SS + blk * 32) * 64;
    {
        int r = tid >> 3, c8 = (tid & 7) * 8;
        BF8 a; a.u4 = *reinterpret_cast<const uint4*>(vb + (size_t)r * 64 + c8);
        #pragma unroll
        for (int t = 0; t < 8; t++) vs[r][c8 + t] = bf2f(a.h[t]);
    }
    __syncthreads();
    if (tid < 32) {
        float zs = 0.f;
        #pragma unroll
        for (int jj = 0; jj < 32; jj++) zs += ps[tid][jj];
        z[(size_t)bh * SS + blk * 32 + tid] = zs;
    }
    int d = tid & 63, i0 = tid >> 6;
    #pragma unroll
    for (int ii = 0; ii < 8; ii++) {
        int i = ii * 4 + i0;
        float a = 0.f;
        #pragma unroll
        for (int jj = 0; jj < 32; jj++) a += ps[i][jj] * vs[jj][d];
        y[((size_t)bh * SS + blk * 32 + i) * 64 + d] = a;
    }
}

// ---------------- level-l PV with repeat-accumulate into full-res y,z ----------------
__global__ __launch_bounds__(256) void pvL_kernel(
    const float* __restrict__ simr, const float* __restrict__ siml,
    const bfu* __restrict__ vc, const float* __restrict__ mval,
    float* __restrict__ y, float* __restrict__ z, int p, int rows, int l)
{
    int bid = blockIdx.x;
    int g2 = bid % (2 * p); int bh = bid / (2 * p);
    int dir = g2 & 1, g = g2 >> 1;
    float m = mval[bh];
    const float* sp = (dir ? siml : simr) + ((size_t)(bh * p + g)) * 1024;
    __shared__ float ps[32][33];
    __shared__ float vs[32][65];
    int tid = threadIdx.x;
    {
        float4 s4 = reinterpret_cast<const float4*>(sp)[tid];
        int r = tid >> 3, c4 = (tid & 7) * 4;
        ps[r][c4 + 0] = expf(s4.x - m); ps[r][c4 + 1] = expf(s4.y - m);
        ps[r][c4 + 2] = expf(s4.z - m); ps[r][c4 + 3] = expf(s4.w - m);
    }
    const bfu* vb = vc + ((size_t)bh * rows + g * 64 + (1 - dir) * 32) * 64;
    {
        int r = tid >> 3, c8 = (tid & 7) * 8;
        BF8 a; a.u4 = *reinterpret_cast<const uint4*>(vb + (size_t)r * 64 + c8);
        #pragma unroll
        for (int t = 0; t < 8; t++) vs[r][c8 + t] = bf2f(a.h[t]);
    }
    __syncthreads();
    int rep = 1 << l;
    if (tid < 32) {
        float zs = 0.f;
        #pragma unroll
        for (int jj = 0; jj < 32; jj++) zs += ps[tid][jj];
        int cr = g * 64 + dir * 32 + tid;
        size_t base = (size_t)bh * SS + ((size_t)cr << l);
        for (int t = 0; t < rep; t++) z[base + t] += zs;
    }
    int d = tid & 63, i0 = tid >> 6;
    #pragma unroll
    for (int ii = 0; ii < 8; ii++) {
        int i = ii * 4 + i0;
        float a = 0.f;
        #pragma unroll
        for (int jj = 0; jj < 32; jj++) a += ps[i][jj] * vs[jj][d];
        int cr = g * 64 + dir * 32 + i;
        size_t base = ((size_t)bh * SS + ((size_t)cr << l)) * 64 + d;
        for (int t = 0; t < rep; t++) y[base + (size_t)t * 64] += a;
    }
}

// ---------------- output projection GEMM with fused y/z divide ----------------
__global__ __launch_bounds__(256) void gemm_out_kernel(
    const float* __restrict__ y, const float* __restrict__ z,
    const float* __restrict__ Wo, const float* __restrict__ bo,
    float* __restrict__ out)
{
    __shared__ float As[16][128];
    __shared__ float Bs[16][128];
    int tid = threadIdx.x;
    int nt = blockIdx.x;   // 0..7
    int mt = blockIdx.y;   // 0..127
    int row0 = mt * 128, n0 = nt * 128;
    int b = row0 >> 12, s0 = row0 & 4095;
    int tx = tid & 15, ty = tid >> 4;
    float acc[8][8] = {};

    for (int k0 = 0; k0 < 1024; k0 += 16) {
        int h = k0 >> 6, dh0 = k0 & 63;
        const float* ybase = y + ((size_t)(b * HH + h) * SS + s0) * 64 + dh0;
        const float* zbase = z + (size_t)(b * HH + h) * SS + s0;
        #pragma unroll
        for (int i2 = 0; i2 < 2; i2++) {
            int idx = tid * 2 + i2;
            int r = idx >> 2, c4 = (idx & 3) * 4;
            float4 a = *reinterpret_cast<const float4*>(ybase + (size_t)r * 64 + c4);
            float inv = 1.0f / zbase[r];
            As[c4 + 0][r] = a.x * inv; As[c4 + 1][r] = a.y * inv;
            As[c4 + 2][r] = a.z * inv; As[c4 + 3][r] = a.w * inv;
        }
        #pragma unroll
        for (int i2 = 0; i2 < 2; i2++) {
            int idx = tid * 2 + i2;
            int r = idx >> 5, c4 = (idx & 31) * 4;
            *reinterpret_cast<float4*>(&Bs[r][c4]) =
                *reinterpret_cast<const float4*>(&Wo[(size_t)(k0 + r) * 1024 + n0 + c4]);
        }
        __syncthreads();
        #pragma unroll
        for (int kk = 0; kk < 16; kk++) {
            float a[8], bb[8];
            #pragma unroll
            for (int i = 0; i < 8; i++) a[i] = As[kk][ty * 8 + i];
            #pragma unroll
            for (int j = 0; j < 8; j++) bb[j] = Bs[kk][tx * 8 + j];
            #pragma unroll
            for (int i = 0; i < 8; i++)
                #pragma unroll
                for (int j = 0; j < 8; j++)
                    acc[i][j] += a[i] * bb[j];
        }
        __syncthreads();
    }
    #pragma unroll
    for (int i = 0; i < 8; i++) {
        int row = row0 + ty * 8 + i;
        #pragma unroll
        for (int j = 0; j < 8; j++) {
            int n = n0 + tx * 8 + j;
            out[(size_t)row * 1024 + n] = acc[i][j] + bo[n];
        }
    }
}

extern "C" void kernel_launch(void* const* d_in, const int* in_sizes, int n_in,
                              void* d_out, int out_size, void* d_ws, size_t ws_size,
                              hipStream_t stream)
{
    const float* x   = (const float*)d_in[0];
    const float* wq  = (const float*)d_in[1];
    const float* bq  = (const float*)d_in[2];
    const float* wk  = (const float*)d_in[3];
    const float* bk  = (const float*)d_in[4];
    const float* wv  = (const float*)d_in[5];
    const float* bv  = (const float*)d_in[6];
    const float* rpb = (const float*)d_in[7];
    const float* wo  = (const float*)d_in[8];
    const float* bo  = (const float*)d_in[9];
    float* out = (float*)d_out;

    const size_t NEED = 267387392ULL;   // 255.0 MiB
    if (ws_size < NEED) {
        // Diagnostic: report ws_size (in MiB) through the absmax error instead of crashing.
        float val = (float)(ws_size >> 20);
        int n = out_size;
        hipLaunchKernelGGL(diag_kernel, dim3((n + 255) / 256), dim3(256), 0, stream, out, val, n);
        return;
    }

    char* w8 = (char*)d_ws;
    bfu* q    = (bfu*)(w8);                       // 33,554,432 B
    bfu* k    = (bfu*)(w8 + 33554432);            // 33,554,432 B
    bfu* v    = (bfu*)(w8 + 67108864);            // 33,554,432 B
    bfu* qc   = (bfu*)(w8 + 100663296);           // 33,030,144 B
    bfu* kc   = (bfu*)(w8 + 133693440);           // 33,030,144 B
    bfu* vc   = (bfu*)(w8 + 166723584);           // 33,030,144 B
    float* sim0 = (float*)(w8 + 199753728);       // 33,554,432 B
    float* simr = (float*)(w8 + 233308160);       // 16,515,072 B
    float* siml = (float*)(w8 + 249823232);       // 16,515,072 B
    float* zbuf = (float*)(w8 + 266338304);       //  1,048,576 B
    unsigned* m_enc = (unsigned*)(w8 + 267386880);
    float* m_val    = (float*)(w8 + 267387136);
    float* y = (float*)(w8);                      // 67,108,864 B alias over q,k (dead after sims)

    // 1. QKV projection (f32 compute, bf16 store)
    hipLaunchKernelGGL(gemm_qkv_kernel, dim3(24, 128), dim3(256), 0, stream,
                       x, wq, wk, wv, bq, bk, bv, q, k, v);

    // 2. coarsen pyramid (bf16, element offsets)
    static const size_t GOFF[7] = {0, 0, 8388608, 12582912, 14680064, 15728640, 16252928};
    const bfu* qin = q; const bfu* kin = k; const bfu* vin = v;
    for (int l = 1; l <= 6; l++) {
        bfu* qo = qc + GOFF[l]; bfu* ko = kc + GOFF[l]; bfu* vo = vc + GOFF[l];
        int n4 = BH * (SS >> l) * 8;              // 8-elem chunks per tensor
        int blocks = (3 * n4 + 255) / 256;
        hipLaunchKernelGGL(coarsen3_kernel, dim3(blocks), dim3(256), 0, stream,
                           qin, kin, vin, qo, ko, vo, n4);
        qin = qo; kin = ko; vin = vo;
    }

    // 3. similarities + global max
    hipMemsetAsync(m_enc, 0, 64 * sizeof(unsigned), stream);
    hipLaunchKernelGGL(sim0_kernel, dim3(8192), dim3(256), 0, stream, q, k, rpb, sim0, m_enc);
    static const size_t SOFF[7] = {0, 0, 2097152, 3145728, 3670016, 3932160, 4063232};
    for (int l = 1; l <= 6; l++) {
        int p = 64 >> l, rows = SS >> l;
        hipLaunchKernelGGL(simL_kernel, dim3(BH * p * 2), dim3(256), 0, stream,
                           qc + GOFF[l], kc + GOFF[l], rpb + (size_t)l * 127 * 16,
                           simr + SOFF[l], siml + SOFF[l], m_enc, p, rows);
    }
    hipLaunchKernelGGL(maxfin_kernel, dim3(1), dim3(64), 0, stream, m_enc, m_val);

    // 4. PV accumulate (pv0 initializes y,z over dead q,k; levels accumulate, stream-ordered)
    hipLaunchKernelGGL(pv0_kernel, dim3(8192), dim3(256), 0, stream, sim0, v, m_val, y, zbuf);
    for (int l = 1; l <= 6; l++) {
        int p = 64 >> l, rows = SS >> l;
        hipLaunchKernelGGL(pvL_kernel, dim3(BH * p * 2), dim3(256), 0, stream,
                           simr + SOFF[l], siml + SOFF[l], vc + GOFF[l], m_val, y, zbuf, p, rows, l);
    }

    // 5. output projection (divide fused into A-load)
    hipLaunchKernelGGL(gemm_out_kernel, dim3(8, 128), dim3(256), 0, stream, y, zbuf, wo, bo, out);
}

// Round 5
// 877.661 us; speedup vs baseline: 2.4678x; 2.4678x over previous
//
#include <hip/hip_runtime.h>
#include <cstdint>
#include <cstddef>

#define SS 4096
#define HH 16
#define BH 64   // B*H

typedef unsigned short bfu;
typedef __attribute__((ext_vector_type(8))) short short8;
typedef __attribute__((ext_vector_type(4))) float f32x4;

__device__ __forceinline__ float bf2f(bfu u) { return __uint_as_float(((unsigned)u) << 16); }
__device__ __forceinline__ bfu f2bf(float f) {
    unsigned u = __float_as_uint(f);
    return (bfu)((u + 0x7fffu + ((u >> 16) & 1u)) >> 16);
}
union BF8 { uint4 u4; bfu h[8]; short8 s8; };

__device__ __forceinline__ unsigned encf(float x) {
    unsigned u = __float_as_uint(x);
    return (u & 0x80000000u) ? ~u : (u | 0x80000000u);
}
__device__ __forceinline__ float decf(unsigned u) {
    return (u & 0x80000000u) ? __uint_as_float(u & 0x7fffffffu) : __uint_as_float(~u);
}

__device__ __forceinline__ void gload_lds16(const bfu* g, bfu* l) {
    __builtin_amdgcn_global_load_lds(
        (const __attribute__((address_space(1))) void*)g,
        (__attribute__((address_space(3))) void*)l,
        16, 0, 0);
}

__global__ void diag_kernel(float* __restrict__ out, float val, int n) {
    int i = blockIdx.x * 256 + threadIdx.x;
    if (i < n) out[i] = val;
}

// ---------------- f32 -> bf16 elementwise (x) ----------------
__global__ __launch_bounds__(256) void f32_to_bf16_kernel(
    const float* __restrict__ in, bfu* __restrict__ out, int n8)
{
    int t = blockIdx.x * 256 + threadIdx.x;
    if (t >= n8) return;
    float4 a = reinterpret_cast<const float4*>(in)[(size_t)t * 2];
    float4 b = reinterpret_cast<const float4*>(in)[(size_t)t * 2 + 1];
    BF8 p;
    p.h[0] = f2bf(a.x); p.h[1] = f2bf(a.y); p.h[2] = f2bf(a.z); p.h[3] = f2bf(a.w);
    p.h[4] = f2bf(b.x); p.h[5] = f2bf(b.y); p.h[6] = f2bf(b.z); p.h[7] = f2bf(b.w);
    reinterpret_cast<uint4*>(out)[t] = p.u4;
}

// ---------------- 1024x1024 f32 [K][N] -> bf16 [N][K] transpose ----------------
__global__ __launch_bounds__(256) void transpose_w_kernel(
    const float* __restrict__ src, bfu* __restrict__ dst)
{
    __shared__ float t[32][33];
    int tx = threadIdx.x & 31, ty = threadIdx.x >> 5;   // 32x8
    int n0 = blockIdx.x * 32, k0 = blockIdx.y * 32;
    #pragma unroll
    for (int i = 0; i < 4; i++)
        t[ty + 8 * i][tx] = src[(size_t)(k0 + ty + 8 * i) * 1024 + n0 + tx];
    __syncthreads();
    #pragma unroll
    for (int i = 0; i < 4; i++)
        dst[(size_t)(n0 + ty + 8 * i) * 1024 + k0 + tx] = f2bf(t[tx][ty + 8 * i]);
}

// ---------------- normalize y/z -> bf16 A matrix [16384][1024] ----------------
__global__ __launch_bounds__(256) void conv_y_kernel(
    const float* __restrict__ y, const float* __restrict__ z, bfu* __restrict__ yA)
{
    int t = blockIdx.x * 256 + threadIdx.x;   // 2,097,152 total
    int bh = t >> 15; int rem = t & 32767; int s = rem >> 3; int c8 = rem & 7;
    const float* yp = y + (((size_t)bh * SS + s) * 64 + c8 * 8);
    float inv = 1.0f / z[(size_t)bh * SS + s];
    float4 a = reinterpret_cast<const float4*>(yp)[0];
    float4 b = reinterpret_cast<const float4*>(yp)[1];
    BF8 p;
    p.h[0] = f2bf(a.x * inv); p.h[1] = f2bf(a.y * inv); p.h[2] = f2bf(a.z * inv); p.h[3] = f2bf(a.w * inv);
    p.h[4] = f2bf(b.x * inv); p.h[5] = f2bf(b.y * inv); p.h[6] = f2bf(b.z * inv); p.h[7] = f2bf(b.w * inv);
    size_t off = ((size_t)(bh >> 4) * SS + s) * 1024 + (bh & 15) * 64 + c8 * 8;
    *reinterpret_cast<uint4*>(yA + off) = p.u4;
}

// ---------------- MFMA QKV GEMM: A[16384][1024] @ Bt[3072][1024]^T -> q,k,v bf16 ----------------
__global__ __launch_bounds__(256) void gemm_qkv_mfma(
    const bfu* __restrict__ A, const bfu* __restrict__ Bt,
    const float* __restrict__ bq, const float* __restrict__ bk, const float* __restrict__ bv,
    bfu* __restrict__ q, bfu* __restrict__ k, bfu* __restrict__ v)
{
    __shared__ __align__(16) bfu As[128 * 32];
    __shared__ __align__(16) bfu Bs[128 * 32];
    int tid = threadIdx.x;
    int w = tid >> 6, lane = tid & 63;
    int row0 = blockIdx.y * 128;
    int col0 = blockIdx.x * 128;

    int srow = lane >> 2;       // row within 16-row staging group
    int scg  = lane & 3;        // LDS chunk slot this lane fills

    f32x4 acc[4][4];
    #pragma unroll
    for (int i = 0; i < 4; i++)
        #pragma unroll
        for (int j = 0; j < 4; j++)
            acc[i][j] = (f32x4){0.f, 0.f, 0.f, 0.f};

    int wm = (w >> 1) * 64, wn = (w & 1) * 64;
    int l15 = lane & 15, lk = lane >> 4;

    for (int k0 = 0; k0 < 1024; k0 += 32) {
        #pragma unroll
        for (int i = 0; i < 2; i++) {
            int r = w * 32 + i * 16 + srow;
            int cg = scg ^ ((r >> 1) & 3);     // pre-swizzled global chunk
            gload_lds16(A  + (size_t)(row0 + r) * 1024 + k0 + cg * 8, &As[(w * 32 + i * 16) * 32]);
            gload_lds16(Bt + (size_t)(col0 + r) * 1024 + k0 + cg * 8, &Bs[(w * 32 + i * 16) * 32]);
        }
        __syncthreads();
        short8 a[4], b[4];
        #pragma unroll
        for (int mi = 0; mi < 4; mi++) {
            int r = wm + mi * 16 + l15;
            int cs = lk ^ ((r >> 1) & 3);
            a[mi] = *reinterpret_cast<const short8*>(&As[r * 32 + cs * 8]);
        }
        #pragma unroll
        for (int ni = 0; ni < 4; ni++) {
            int r = wn + ni * 16 + l15;
            int cs = lk ^ ((r >> 1) & 3);
            b[ni] = *reinterpret_cast<const short8*>(&Bs[r * 32 + cs * 8]);
        }
        #pragma unroll
        for (int mi = 0; mi < 4; mi++)
            #pragma unroll
            for (int ni = 0; ni < 4; ni++)
                acc[mi][ni] = __builtin_amdgcn_mfma_f32_16x16x32_bf16(a[mi], b[ni], acc[mi][ni], 0, 0, 0);
        __syncthreads();
    }

    int tsel = col0 >> 10;
    const float* bias = tsel == 0 ? bq : (tsel == 1 ? bk : bv);
    bfu* Out          = tsel == 0 ? q  : (tsel == 1 ? k  : v);
    float scale = tsel == 0 ? 0.125f : 1.0f;
    #pragma unroll
    for (int ni = 0; ni < 4; ni++) {
        int nl = (col0 & 1023) + wn + ni * 16 + l15;
        float bb = bias[nl];
        int h = nl >> 6, dh = nl & 63;
        #pragma unroll
        for (int mi = 0; mi < 4; mi++) {
            #pragma unroll
            for (int r = 0; r < 4; r++) {
                int row = row0 + wm + mi * 16 + lk * 4 + r;
                int bI = row >> 12, s = row & 4095;
                Out[((size_t)(bI * HH + h) * SS + s) * 64 + dh] = f2bf((acc[mi][ni][r] + bb) * scale);
            }
        }
    }
}

// ---------------- MFMA output GEMM: yA[16384][1024] @ Wot[1024][1024]^T -> out f32 ----------------
__global__ __launch_bounds__(256) void gemm_out_mfma(
    const bfu* __restrict__ A, const bfu* __restrict__ Bt,
    const float* __restrict__ bo, float* __restrict__ out)
{
    __shared__ __align__(16) bfu As[128 * 32];
    __shared__ __align__(16) bfu Bs[128 * 32];
    int tid = threadIdx.x;
    int w = tid >> 6, lane = tid & 63;
    int row0 = blockIdx.y * 128;
    int col0 = blockIdx.x * 128;
    int srow = lane >> 2, scg = lane & 3;

    f32x4 acc[4][4];
    #pragma unroll
    for (int i = 0; i < 4; i++)
        #pragma unroll
        for (int j = 0; j < 4; j++)
            acc[i][j] = (f32x4){0.f, 0.f, 0.f, 0.f};

    int wm = (w >> 1) * 64, wn = (w & 1) * 64;
    int l15 = lane & 15, lk = lane >> 4;

    for (int k0 = 0; k0 < 1024; k0 += 32) {
        #pragma unroll
        for (int i = 0; i < 2; i++) {
            int r = w * 32 + i * 16 + srow;
            int cg = scg ^ ((r >> 1) & 3);
            gload_lds16(A  + (size_t)(row0 + r) * 1024 + k0 + cg * 8, &As[(w * 32 + i * 16) * 32]);
            gload_lds16(Bt + (size_t)(col0 + r) * 1024 + k0 + cg * 8, &Bs[(w * 32 + i * 16) * 32]);
        }
        __syncthreads();
        short8 a[4], b[4];
        #pragma unroll
        for (int mi = 0; mi < 4; mi++) {
            int r = wm + mi * 16 + l15;
            int cs = lk ^ ((r >> 1) & 3);
            a[mi] = *reinterpret_cast<const short8*>(&As[r * 32 + cs * 8]);
        }
        #pragma unroll
        for (int ni = 0; ni < 4; ni++) {
            int r = wn + ni * 16 + l15;
            int cs = lk ^ ((r >> 1) & 3);
            b[ni] = *reinterpret_cast<const short8*>(&Bs[r * 32 + cs * 8]);
        }
        #pragma unroll
        for (int mi = 0; mi < 4; mi++)
            #pragma unroll
            for (int ni = 0; ni < 4; ni++)
                acc[mi][ni] = __builtin_amdgcn_mfma_f32_16x16x32_bf16(a[mi], b[ni], acc[mi][ni], 0, 0, 0);
        __syncthreads();
    }

    #pragma unroll
    for (int ni = 0; ni < 4; ni++) {
        int n = col0 + wn + ni * 16 + l15;
        float bb = bo[n];
        #pragma unroll
        for (int mi = 0; mi < 4; mi++) {
            #pragma unroll
            for (int r = 0; r < 4; r++) {
                int row = row0 + wm + mi * 16 + lk * 4 + r;
                out[(size_t)row * 1024 + n] = acc[mi][ni][r] + bb;
            }
        }
    }
}

// ---------------- coarsen (mean of adjacent row pairs), q/k/v fused, bf16 ----------------
__global__ void coarsen3_kernel(const bfu* __restrict__ qi, const bfu* __restrict__ ki,
                                const bfu* __restrict__ vi,
                                bfu* __restrict__ qo, bfu* __restrict__ ko,
                                bfu* __restrict__ vo, int n4)
{
    int idx = blockIdx.x * 256 + threadIdx.x;
    if (idx >= 3 * n4) return;
    int sel = idx / n4;
    int e = idx - sel * n4;
    const bfu* in = sel == 0 ? qi : (sel == 1 ? ki : vi);
    bfu* out      = sel == 0 ? qo : (sel == 1 ? ko : vo);
    int R = e >> 3, c = e & 7;
    BF8 a, b, o;
    a.u4 = reinterpret_cast<const uint4*>(in)[(size_t)(2 * R) * 8 + c];
    b.u4 = reinterpret_cast<const uint4*>(in)[(size_t)(2 * R + 1) * 8 + c];
    #pragma unroll
    for (int t = 0; t < 8; t++)
        o.h[t] = f2bf(0.5f * (bf2f(a.h[t]) + bf2f(b.h[t])));
    reinterpret_cast<uint4*>(out)[e] = o.u4;
}

// ---------------- level-0 similarity (diagonal 32x32 blocks) ----------------
__global__ __launch_bounds__(256) void sim0_kernel(
    const bfu* __restrict__ q, const bfu* __restrict__ k,
    const float* __restrict__ rpb0, float* __restrict__ sim0, unsigned* __restrict__ m_enc)
{
    int bid = blockIdx.x;
    int blk = bid & 127, bh = bid >> 7;
    int h = bh & 15;
    const bfu* qb = q + ((size_t)bh * SS + blk * 32) * 64;
    const bfu* kb = k + ((size_t)bh * SS + blk * 32) * 64;
    __shared__ float qs[32][65], ks[32][65];
    int tid = threadIdx.x;
    {
        int r = tid >> 3, c8 = (tid & 7) * 8;
        BF8 a; a.u4 = *reinterpret_cast<const uint4*>(qb + (size_t)r * 64 + c8);
        BF8 b; b.u4 = *reinterpret_cast<const uint4*>(kb + (size_t)r * 64 + c8);
        #pragma unroll
        for (int t = 0; t < 8; t++) { qs[r][c8 + t] = bf2f(a.h[t]); ks[r][c8 + t] = bf2f(b.h[t]); }
    }
    __syncthreads();
    int j = tid & 31, i4 = tid >> 5;
    float acc[4] = {0.f, 0.f, 0.f, 0.f};
    for (int d = 0; d < 64; d++) {
        float kv = ks[j][d];
        #pragma unroll
        for (int ii = 0; ii < 4; ii++) acc[ii] += qs[i4 * 4 + ii][d] * kv;
    }
    float lmax = -1e30f;
    float* so = sim0 + (size_t)bid * 1024;
    #pragma unroll
    for (int ii = 0; ii < 4; ii++) {
        int i = i4 * 4 + ii;
        float sv = acc[ii] + rpb0[((j - i) + 63) * 16 + h];
        so[i * 32 + j] = sv;
        lmax = fmaxf(lmax, sv);
    }
    for (int off = 32; off > 0; off >>= 1) lmax = fmaxf(lmax, __shfl_down(lmax, off));
    __shared__ float wm[4];
    if ((tid & 63) == 0) wm[tid >> 6] = lmax;
    __syncthreads();
    if (tid == 0) {
        float m2 = fmaxf(fmaxf(wm[0], wm[1]), fmaxf(wm[2], wm[3]));
        atomicMax(&m_enc[bh], encf(m2));
    }
}

// ---------------- level-l sibling cross similarities ----------------
__global__ __launch_bounds__(256) void simL_kernel(
    const bfu* __restrict__ qc, const bfu* __restrict__ kc,
    const float* __restrict__ rpbl, float* __restrict__ simr, float* __restrict__ siml,
    unsigned* __restrict__ m_enc, int p, int rows)
{
    int bid = blockIdx.x;
    int g2 = bid % (2 * p); int bh = bid / (2 * p);
    int dir = g2 & 1, g = g2 >> 1;
    int h = bh & 15;
    const bfu* qb = qc + ((size_t)bh * rows + g * 64 + dir * 32) * 64;
    const bfu* kb = kc + ((size_t)bh * rows + g * 64 + (1 - dir) * 32) * 64;
    __shared__ float qs[32][65], ks[32][65];
    int tid = threadIdx.x;
    {
        int r = tid >> 3, c8 = (tid & 7) * 8;
        BF8 a; a.u4 = *reinterpret_cast<const uint4*>(qb + (size_t)r * 64 + c8);
        BF8 b; b.u4 = *reinterpret_cast<const uint4*>(kb + (size_t)r * 64 + c8);
        #pragma unroll
        for (int t = 0; t < 8; t++) { qs[r][c8 + t] = bf2f(a.h[t]); ks[r][c8 + t] = bf2f(b.h[t]); }
    }
    __syncthreads();
    int j = tid & 31, i4 = tid >> 5;
    float acc[4] = {0.f, 0.f, 0.f, 0.f};
    for (int d = 0; d < 64; d++) {
        float kv = ks[j][d];
        #pragma unroll
        for (int ii = 0; ii < 4; ii++) acc[ii] += qs[i4 * 4 + ii][d] * kv;
    }
    int boff = dir ? 31 : 95;
    float* so = (dir ? siml : simr) + ((size_t)(bh * p + g)) * 1024;
    float lmax = -1e30f;
    #pragma unroll
    for (int ii = 0; ii < 4; ii++) {
        int i = i4 * 4 + ii;
        float sv = acc[ii] + rpbl[((j - i) + boff) * 16 + h];
        so[i * 32 + j] = sv;
        lmax = fmaxf(lmax, sv);
    }
    for (int off = 32; off > 0; off >>= 1) lmax = fmaxf(lmax, __shfl_down(lmax, off));
    __shared__ float wm[4];
    if ((tid & 63) == 0) wm[tid >> 6] = lmax;
    __syncthreads();
    if (tid == 0) {
        float m2 = fmaxf(fmaxf(wm[0], wm[1]), fmaxf(wm[2], wm[3]));
        atomicMax(&m_enc[bh], encf(m2));
    }
}

__global__ void maxfin_kernel(const unsigned* __restrict__ me, float* __restrict__ mv)
{
    int i = threadIdx.x;
    if (i < 64) mv[i] = 3.0f * decf(me[i]);
}

// ---------------- level-0 PV: y,z initialized here ----------------
__global__ __launch_bounds__(256) void pv0_kernel(
    const float* __restrict__ sim0, const bfu* __restrict__ v,
    const float* __restrict__ mval, float* __restrict__ y, float* __restrict__ z)
{
    int bid = blockIdx.x;
    int blk = bid & 127, bh = bid >> 7;
    float m = mval[bh];
    __shared__ float ps[32][33];
    __shared__ float vs[32][65];
    int tid = threadIdx.x;
    {
        float4 s4 = reinterpret_cast<const float4*>(sim0 + (size_t)bid * 1024)[tid];
        int r = tid >> 3, c4 = (tid & 7) * 4;
        ps[r][c4 + 0] = expf(s4.x - m); ps[r][c4 + 1] = expf(s4.y - m);
        ps[r][c4 + 2] = expf(s4.z - m); ps[r][c4 + 3] = expf(s4.w - m);
    }
    const bfu* vb = v + ((size_t)bh * SS + blk * 32) * 64;
    {
        int r = tid >> 3, c8 = (tid & 7) * 8;
        BF8 a; a.u4 = *reinterpret_cast<const uint4*>(vb + (size_t)r * 64 + c8);
        #pragma unroll
        for (int t = 0; t < 8; t++) vs[r][c8 + t] = bf2f(a.h[t]);
    }
    __syncthreads();
    if (tid < 32) {
        float zs = 0.f;
        #pragma unroll
        for (int jj = 0; jj < 32; jj++) zs += ps[tid][jj];
        z[(size_t)bh * SS + blk * 32 + tid] = zs;
    }
    int d = tid & 63, i0 = tid >> 6;
    #pragma unroll
    for (int ii = 0; ii < 8; ii++) {
        int i = ii * 4 + i0;
        float a = 0.f;
        #pragma unroll
        for (int jj = 0; jj < 32; jj++) a += ps[i][jj] * vs[jj][d];
        y[((size_t)bh * SS + blk * 32 + i) * 64 + d] = a;
    }
}

// ---------------- level-l PV with repeat-accumulate into full-res y,z ----------------
__global__ __launch_bounds__(256) void pvL_kernel(
    const float* __restrict__ simr, const float* __restrict__ siml,
    const bfu* __restrict__ vc, const float* __restrict__ mval,
    float* __restrict__ y, float* __restrict__ z, int p, int rows, int l)
{
    int bid = blockIdx.x;
    int g2 = bid % (2 * p); int bh = bid / (2 * p);
    int dir = g2 & 1, g = g2 >> 1;
    float m = mval[bh];
    const float* sp = (dir ? siml : simr) + ((size_t)(bh * p + g)) * 1024;
    __shared__ float ps[32][33];
    __shared__ float vs[32][65];
    int tid = threadIdx.x;
    {
        float4 s4 = reinterpret_cast<const float4*>(sp)[tid];
        int r = tid >> 3, c4 = (tid & 7) * 4;
        ps[r][c4 + 0] = expf(s4.x - m); ps[r][c4 + 1] = expf(s4.y - m);
        ps[r][c4 + 2] = expf(s4.z - m); ps[r][c4 + 3] = expf(s4.w - m);
    }
    const bfu* vb = vc + ((size_t)bh * rows + g * 64 + (1 - dir) * 32) * 64;
    {
        int r = tid >> 3, c8 = (tid & 7) * 8;
        BF8 a; a.u4 = *reinterpret_cast<const uint4*>(vb + (size_t)r * 64 + c8);
        #pragma unroll
        for (int t = 0; t < 8; t++) vs[r][c8 + t] = bf2f(a.h[t]);
    }
    __syncthreads();
    int rep = 1 << l;
    if (tid < 32) {
        float zs = 0.f;
        #pragma unroll
        for (int jj = 0; jj < 32; jj++) zs += ps[tid][jj];
        int cr = g * 64 + dir * 32 + tid;
        size_t base = (size_t)bh * SS + ((size_t)cr << l);
        for (int t = 0; t < rep; t++) z[base + t] += zs;
    }
    int d = tid & 63, i0 = tid >> 6;
    #pragma unroll
    for (int ii = 0; ii < 8; ii++) {
        int i = ii * 4 + i0;
        float a = 0.f;
        #pragma unroll
        for (int jj = 0; jj < 32; jj++) a += ps[i][jj] * vs[jj][d];
        int cr = g * 64 + dir * 32 + i;
        size_t base = ((size_t)bh * SS + ((size_t)cr << l)) * 64 + d;
        for (int t = 0; t < rep; t++) y[base + (size_t)t * 64] += a;
    }
}

extern "C" void kernel_launch(void* const* d_in, const int* in_sizes, int n_in,
                              void* d_out, int out_size, void* d_ws, size_t ws_size,
                              hipStream_t stream)
{
    const float* x   = (const float*)d_in[0];
    const float* wq  = (const float*)d_in[1];
    const float* bq  = (const float*)d_in[2];
    const float* wk  = (const float*)d_in[3];
    const float* bk  = (const float*)d_in[4];
    const float* wv  = (const float*)d_in[5];
    const float* bv  = (const float*)d_in[6];
    const float* rpb = (const float*)d_in[7];
    const float* wo  = (const float*)d_in[8];
    const float* bo  = (const float*)d_in[9];
    float* out = (float*)d_out;

    const size_t NEED = 267387392ULL;   // 255.0 MiB
    if (ws_size < NEED) {
        float val = (float)(ws_size >> 20);
        int n = out_size;
        hipLaunchKernelGGL(diag_kernel, dim3((n + 255) / 256), dim3(256), 0, stream, out, val, n);
        return;
    }

    char* w8 = (char*)d_ws;
    bfu* q    = (bfu*)(w8);                       // 33,554,432 B
    bfu* k    = (bfu*)(w8 + 33554432);
    bfu* v    = (bfu*)(w8 + 67108864);
    bfu* qc   = (bfu*)(w8 + 100663296);           // 33,030,144 B
    bfu* kc   = (bfu*)(w8 + 133693440);
    bfu* vc   = (bfu*)(w8 + 166723584);
    float* sim0 = (float*)(w8 + 199753728);       // 33,554,432 B
    float* simr = (float*)(w8 + 233308160);       // 16,515,072 B
    float* siml = (float*)(w8 + 249823232);       // 16,515,072 B
    float* zbuf = (float*)(w8 + 266338304);       //  1,048,576 B
    unsigned* m_enc = (unsigned*)(w8 + 267386880);
    float* m_val    = (float*)(w8 + 267387136);
    float* y = (float*)(w8);                      // f32 alias over q,k (dead after sims)
    // transient aliases (lifetimes disjoint from sims):
    bfu* xbf    = (bfu*)sim0;                     // stages 1-2 (33.5 MB, sim0 written later)
    bfu* wqkv_t = (bfu*)simr;                     // stages 1-2 (6.3 MB in simr slot)
    bfu* yA     = (bfu*)sim0;                     // stages 6-7 (sim0 dead after pv0)
    bfu* wot    = (bfu*)simr;                     // stages 6-7 (simr dead after pvL)

    // 1. bf16 conversions: x, and transposed weights [N][K]
    hipLaunchKernelGGL(f32_to_bf16_kernel, dim3(8192), dim3(256), 0, stream, x, xbf, 2097152);
    hipLaunchKernelGGL(transpose_w_kernel, dim3(32, 32), dim3(256), 0, stream, wq, wqkv_t);
    hipLaunchKernelGGL(transpose_w_kernel, dim3(32, 32), dim3(256), 0, stream, wk, wqkv_t + 1048576);
    hipLaunchKernelGGL(transpose_w_kernel, dim3(32, 32), dim3(256), 0, stream, wv, wqkv_t + 2097152);

    // 2. QKV projection (bf16 MFMA)
    hipLaunchKernelGGL(gemm_qkv_mfma, dim3(24, 128), dim3(256), 0, stream,
                       xbf, wqkv_t, bq, bk, bv, q, k, v);

    // 3. coarsen pyramid
    static const size_t GOFF[7] = {0, 0, 8388608, 12582912, 14680064, 15728640, 16252928};
    const bfu* qin = q; const bfu* kin = k; const bfu* vin = v;
    for (int l = 1; l <= 6; l++) {
        bfu* qo = qc + GOFF[l]; bfu* ko = kc + GOFF[l]; bfu* vo = vc + GOFF[l];
        int n4 = BH * (SS >> l) * 8;
        int blocks = (3 * n4 + 255) / 256;
        hipLaunchKernelGGL(coarsen3_kernel, dim3(blocks), dim3(256), 0, stream,
                           qin, kin, vin, qo, ko, vo, n4);
        qin = qo; kin = ko; vin = vo;
    }

    // 4. similarities + global max
    hipMemsetAsync(m_enc, 0, 64 * sizeof(unsigned), stream);
    hipLaunchKernelGGL(sim0_kernel, dim3(8192), dim3(256), 0, stream, q, k, rpb, sim0, m_enc);
    static const size_t SOFF[7] = {0, 0, 2097152, 3145728, 3670016, 3932160, 4063232};
    for (int l = 1; l <= 6; l++) {
        int p = 64 >> l, rows = SS >> l;
        hipLaunchKernelGGL(simL_kernel, dim3(BH * p * 2), dim3(256), 0, stream,
                           qc + GOFF[l], kc + GOFF[l], rpb + (size_t)l * 127 * 16,
                           simr + SOFF[l], siml + SOFF[l], m_enc, p, rows);
    }
    hipLaunchKernelGGL(maxfin_kernel, dim3(1), dim3(64), 0, stream, m_enc, m_val);

    // 5. PV accumulate (pv0 initializes y,z over dead q,k; levels accumulate)
    hipLaunchKernelGGL(pv0_kernel, dim3(8192), dim3(256), 0, stream, sim0, v, m_val, y, zbuf);
    for (int l = 1; l <= 6; l++) {
        int p = 64 >> l, rows = SS >> l;
        hipLaunchKernelGGL(pvL_kernel, dim3(BH * p * 2), dim3(256), 0, stream,
                           simr + SOFF[l], siml + SOFF[l], vc + GOFF[l], m_val, y, zbuf, p, rows, l);
    }

    // 6. normalize + bf16 convert y, transpose Wo
    hipLaunchKernelGGL(conv_y_kernel, dim3(8192), dim3(256), 0, stream, y, zbuf, yA);
    hipLaunchKernelGGL(transpose_w_kernel, dim3(32, 32), dim3(256), 0, stream, wo, wot);

    // 7. output projection (bf16 MFMA)
    hipLaunchKernelGGL(gemm_out_mfma, dim3(8, 128), dim3(256), 0, stream, yA, wot, bo, out);
}

// Round 8
// 729.158 us; speedup vs baseline: 2.9704x; 1.2037x over previous
//
#include <hip/hip_runtime.h>
#include <cstdint>
#include <cstddef>

#define SS 4096
#define HH 16
#define BH 64   // B*H

typedef unsigned short bfu;
typedef __attribute__((ext_vector_type(8))) short short8;
typedef __attribute__((ext_vector_type(4))) float f32x4;

__device__ __forceinline__ float bf2f(bfu u) { return __uint_as_float(((unsigned)u) << 16); }
__device__ __forceinline__ bfu f2bf(float f) {
    unsigned u = __float_as_uint(f);
    return (bfu)((u + 0x7fffu + ((u >> 16) & 1u)) >> 16);
}
union BF8 { uint4 u4; bfu h[8]; short8 s8; };

__device__ __forceinline__ unsigned encf(float x) {
    unsigned u = __float_as_uint(x);
    return (u & 0x80000000u) ? ~u : (u | 0x80000000u);
}
__device__ __forceinline__ float decf(unsigned u) {
    return (u & 0x80000000u) ? __uint_as_float(u & 0x7fffffffu) : __uint_as_float(~u);
}

__device__ __forceinline__ void gload_lds16(const bfu* g, bfu* l) {
    __builtin_amdgcn_global_load_lds(
        (const __attribute__((address_space(1))) void*)g,
        (__attribute__((address_space(3))) void*)l,
        16, 0, 0);
}

__global__ void diag_kernel(float* __restrict__ out, float val, int n) {
    int i = blockIdx.x * 256 + threadIdx.x;
    if (i < n) out[i] = val;
}

// ---------------- f32 -> bf16 elementwise (x) ----------------
__global__ __launch_bounds__(256) void f32_to_bf16_kernel(
    const float* __restrict__ in, bfu* __restrict__ out, int n8)
{
    int t = blockIdx.x * 256 + threadIdx.x;
    if (t >= n8) return;
    float4 a = reinterpret_cast<const float4*>(in)[(size_t)t * 2];
    float4 b = reinterpret_cast<const float4*>(in)[(size_t)t * 2 + 1];
    BF8 p;
    p.h[0] = f2bf(a.x); p.h[1] = f2bf(a.y); p.h[2] = f2bf(a.z); p.h[3] = f2bf(a.w);
    p.h[4] = f2bf(b.x); p.h[5] = f2bf(b.y); p.h[6] = f2bf(b.z); p.h[7] = f2bf(b.w);
    reinterpret_cast<uint4*>(out)[t] = p.u4;
}

// ---------------- 1024x1024 f32 [K][N] -> bf16 [N][K] transpose ----------------
__global__ __launch_bounds__(256) void transpose_w_kernel(
    const float* __restrict__ src, bfu* __restrict__ dst)
{
    __shared__ float t[32][33];
    int tx = threadIdx.x & 31, ty = threadIdx.x >> 5;   // 32x8
    int n0 = blockIdx.x * 32, k0 = blockIdx.y * 32;
    #pragma unroll
    for (int i = 0; i < 4; i++)
        t[ty + 8 * i][tx] = src[(size_t)(k0 + ty + 8 * i) * 1024 + n0 + tx];
    __syncthreads();
    #pragma unroll
    for (int i = 0; i < 4; i++)
        dst[(size_t)(n0 + ty + 8 * i) * 1024 + k0 + tx] = f2bf(t[tx][ty + 8 * i]);
}

// ---------------- MFMA QKV GEMM: A[16384][1024] @ Bt[3072][1024]^T -> q,k,v bf16 ----------------
__global__ __launch_bounds__(256) void gemm_qkv_mfma(
    const bfu* __restrict__ A, const bfu* __restrict__ Bt,
    const float* __restrict__ bq, const float* __restrict__ bk, const float* __restrict__ bv,
    bfu* __restrict__ q, bfu* __restrict__ k, bfu* __restrict__ v)
{
    __shared__ __align__(16) bfu As[128 * 32];
    __shared__ __align__(16) bfu Bs[128 * 32];
    int tid = threadIdx.x;
    int w = tid >> 6, lane = tid & 63;
    int row0 = blockIdx.y * 128;
    int col0 = blockIdx.x * 128;

    int srow = lane >> 2;
    int scg  = lane & 3;

    f32x4 acc[4][4];
    #pragma unroll
    for (int i = 0; i < 4; i++)
        #pragma unroll
        for (int j = 0; j < 4; j++)
            acc[i][j] = (f32x4){0.f, 0.f, 0.f, 0.f};

    int wm = (w >> 1) * 64, wn = (w & 1) * 64;
    int l15 = lane & 15, lk = lane >> 4;

    for (int k0 = 0; k0 < 1024; k0 += 32) {
        #pragma unroll
        for (int i = 0; i < 2; i++) {
            int r = w * 32 + i * 16 + srow;
            int cg = scg ^ ((r >> 1) & 3);
            gload_lds16(A  + (size_t)(row0 + r) * 1024 + k0 + cg * 8, &As[(w * 32 + i * 16) * 32]);
            gload_lds16(Bt + (size_t)(col0 + r) * 1024 + k0 + cg * 8, &Bs[(w * 32 + i * 16) * 32]);
        }
        __syncthreads();
        short8 a[4], b[4];
        #pragma unroll
        for (int mi = 0; mi < 4; mi++) {
            int r = wm + mi * 16 + l15;
            int cs = lk ^ ((r >> 1) & 3);
            a[mi] = *reinterpret_cast<const short8*>(&As[r * 32 + cs * 8]);
        }
        #pragma unroll
        for (int ni = 0; ni < 4; ni++) {
            int r = wn + ni * 16 + l15;
            int cs = lk ^ ((r >> 1) & 3);
            b[ni] = *reinterpret_cast<const short8*>(&Bs[r * 32 + cs * 8]);
        }
        #pragma unroll
        for (int mi = 0; mi < 4; mi++)
            #pragma unroll
            for (int ni = 0; ni < 4; ni++)
                acc[mi][ni] = __builtin_amdgcn_mfma_f32_16x16x32_bf16(a[mi], b[ni], acc[mi][ni], 0, 0, 0);
        __syncthreads();
    }

    int tsel = col0 >> 10;
    const float* bias = tsel == 0 ? bq : (tsel == 1 ? bk : bv);
    bfu* Out          = tsel == 0 ? q  : (tsel == 1 ? k  : v);
    float scale = tsel == 0 ? 0.125f : 1.0f;
    #pragma unroll
    for (int ni = 0; ni < 4; ni++) {
        int nl = (col0 & 1023) + wn + ni * 16 + l15;
        float bb = bias[nl];
        int h = nl >> 6, dh = nl & 63;
        #pragma unroll
        for (int mi = 0; mi < 4; mi++) {
            #pragma unroll
            for (int r = 0; r < 4; r++) {
                int row = row0 + wm + mi * 16 + lk * 4 + r;
                int bI = row >> 12, s = row & 4095;
                Out[((size_t)(bI * HH + h) * SS + s) * 64 + dh] = f2bf((acc[mi][ni][r] + bb) * scale);
            }
        }
    }
}

// ---------------- MFMA output GEMM: yA[16384][1024] @ Wot[1024][1024]^T -> out f32 ----------------
__global__ __launch_bounds__(256) void gemm_out_mfma(
    const bfu* __restrict__ A, const bfu* __restrict__ Bt,
    const float* __restrict__ bo, float* __restrict__ out)
{
    __shared__ __align__(16) bfu As[128 * 32];
    __shared__ __align__(16) bfu Bs[128 * 32];
    int tid = threadIdx.x;
    int w = tid >> 6, lane = tid & 63;
    int row0 = blockIdx.y * 128;
    int col0 = blockIdx.x * 128;
    int srow = lane >> 2, scg = lane & 3;

    f32x4 acc[4][4];
    #pragma unroll
    for (int i = 0; i < 4; i++)
        #pragma unroll
        for (int j = 0; j < 4; j++)
            acc[i][j] = (f32x4){0.f, 0.f, 0.f, 0.f};

    int wm = (w >> 1) * 64, wn = (w & 1) * 64;
    int l15 = lane & 15, lk = lane >> 4;

    for (int k0 = 0; k0 < 1024; k0 += 32) {
        #pragma unroll
        for (int i = 0; i < 2; i++) {
            int r = w * 32 + i * 16 + srow;
            int cg = scg ^ ((r >> 1) & 3);
            gload_lds16(A  + (size_t)(row0 + r) * 1024 + k0 + cg * 8, &As[(w * 32 + i * 16) * 32]);
            gload_lds16(Bt + (size_t)(col0 + r) * 1024 + k0 + cg * 8, &Bs[(w * 32 + i * 16) * 32]);
        }
        __syncthreads();
        short8 a[4], b[4];
        #pragma unroll
        for (int mi = 0; mi < 4; mi++) {
            int r = wm + mi * 16 + l15;
            int cs = lk ^ ((r >> 1) & 3);
            a[mi] = *reinterpret_cast<const short8*>(&As[r * 32 + cs * 8]);
        }
        #pragma unroll
        for (int ni = 0; ni < 4; ni++) {
            int r = wn + ni * 16 + l15;
            int cs = lk ^ ((r >> 1) & 3);
            b[ni] = *reinterpret_cast<const short8*>(&Bs[r * 32 + cs * 8]);
        }
        #pragma unroll
        for (int mi = 0; mi < 4; mi++)
            #pragma unroll
            for (int ni = 0; ni < 4; ni++)
                acc[mi][ni] = __builtin_amdgcn_mfma_f32_16x16x32_bf16(a[mi], b[ni], acc[mi][ni], 0, 0, 0);
        __syncthreads();
    }

    #pragma unroll
    for (int ni = 0; ni < 4; ni++) {
        int n = col0 + wn + ni * 16 + l15;
        float bb = bo[n];
        #pragma unroll
        for (int mi = 0; mi < 4; mi++) {
            #pragma unroll
            for (int r = 0; r < 4; r++) {
                int row = row0 + wm + mi * 16 + lk * 4 + r;
                out[(size_t)row * 1024 + n] = acc[mi][ni][r] + bb;
            }
        }
    }
}

// ---------------- all-level coarsen: one block = 64 full-res rows -> levels 1..6 ----------------
__global__ __launch_bounds__(256) void coarsen_all_kernel(
    const bfu* __restrict__ qi, const bfu* __restrict__ ki, const bfu* __restrict__ vi,
    bfu* __restrict__ qc, bfu* __restrict__ kc, bfu* __restrict__ vc)
{
    int bid = blockIdx.x;              // sel*4096 + bh*64 + g0
    int sel = bid >> 12;
    int bh = (bid >> 6) & 63;
    int g0 = bid & 63;
    const bfu* in = sel == 0 ? qi : (sel == 1 ? ki : vi);
    bfu* outb     = sel == 0 ? qc : (sel == 1 ? kc : vc);
    __shared__ float bufA[64][64];
    __shared__ float bufB[32][64];
    int tid = threadIdx.x;
    const bfu* src = in + ((size_t)bh * SS + g0 * 64) * 64;
    for (int idx = tid; idx < 64 * 8; idx += 256) {
        int r = idx >> 3, c8 = (idx & 7) * 8;
        BF8 a; a.u4 = *reinterpret_cast<const uint4*>(src + (size_t)r * 64 + c8);
        #pragma unroll
        for (int t = 0; t < 8; t++) bufA[r][c8 + t] = bf2f(a.h[t]);
    }
    __syncthreads();
    const size_t GOFFc[7] = {0, 0, 8388608, 12582912, 14680064, 15728640, 16252928};
    #pragma unroll
    for (int l = 1; l <= 6; l++) {
        int nr = 64 >> l;
        float (*s)[64]   = (l & 1) ? bufA : (float(*)[64])bufB;
        float (*dst)[64] = (l & 1) ? (float(*)[64])bufB : bufA;
        for (int idx = tid; idx < nr * 64; idx += 256) {
            int r = idx >> 6, d = idx & 63;
            float m = 0.5f * (s[2 * r][d] + s[2 * r + 1][d]);
            dst[r][d] = m;
            size_t off = GOFFc[l] + ((size_t)bh * (SS >> l) + g0 * nr + r) * 64 + d;
            outb[off] = f2bf(m);
        }
        __syncthreads();
    }
}

// ---------------- level-0 similarity (diagonal 32x32 blocks) ----------------
__global__ __launch_bounds__(256) void sim0_kernel(
    const bfu* __restrict__ q, const bfu* __restrict__ k,
    const float* __restrict__ rpb0, float* __restrict__ sim0, unsigned* __restrict__ m_enc)
{
    int bid = blockIdx.x;
    int blk = bid & 127, bh = bid >> 7;
    int h = bh & 15;
    const bfu* qb = q + ((size_t)bh * SS + blk * 32) * 64;
    const bfu* kb = k + ((size_t)bh * SS + blk * 32) * 64;
    __shared__ float qs[32][65], ks[32][65];
    int tid = threadIdx.x;
    {
        int r = tid >> 3, c8 = (tid & 7) * 8;
        BF8 a; a.u4 = *reinterpret_cast<const uint4*>(qb + (size_t)r * 64 + c8);
        BF8 b; b.u4 = *reinterpret_cast<const uint4*>(kb + (size_t)r * 64 + c8);
        #pragma unroll
        for (int t = 0; t < 8; t++) { qs[r][c8 + t] = bf2f(a.h[t]); ks[r][c8 + t] = bf2f(b.h[t]); }
    }
    __syncthreads();
    int j = tid & 31, i4 = tid >> 5;
    float acc[4] = {0.f, 0.f, 0.f, 0.f};
    for (int d = 0; d < 64; d++) {
        float kv = ks[j][d];
        #pragma unroll
        for (int ii = 0; ii < 4; ii++) acc[ii] += qs[i4 * 4 + ii][d] * kv;
    }
    float lmax = -1e30f;
    float* so = sim0 + (size_t)bid * 1024;
    #pragma unroll
    for (int ii = 0; ii < 4; ii++) {
        int i = i4 * 4 + ii;
        float sv = acc[ii] + rpb0[((j - i) + 63) * 16 + h];
        so[i * 32 + j] = sv;
        lmax = fmaxf(lmax, sv);
    }
    for (int off = 32; off > 0; off >>= 1) lmax = fmaxf(lmax, __shfl_down(lmax, off));
    __shared__ float wm[4];
    if ((tid & 63) == 0) wm[tid >> 6] = lmax;
    __syncthreads();
    if (tid == 0) {
        float m2 = fmaxf(fmaxf(wm[0], wm[1]), fmaxf(wm[2], wm[3]));
        atomicMax(&m_enc[bh], encf(m2));
    }
}

// ---------------- level-l sibling cross similarities ----------------
__global__ __launch_bounds__(256) void simL_kernel(
    const bfu* __restrict__ qc, const bfu* __restrict__ kc,
    const float* __restrict__ rpbl, float* __restrict__ simr, float* __restrict__ siml,
    unsigned* __restrict__ m_enc, int p, int rows)
{
    int bid = blockIdx.x;
    int g2 = bid % (2 * p); int bh = bid / (2 * p);
    int dir = g2 & 1, g = g2 >> 1;
    int h = bh & 15;
    const bfu* qb = qc + ((size_t)bh * rows + g * 64 + dir * 32) * 64;
    const bfu* kb = kc + ((size_t)bh * rows + g * 64 + (1 - dir) * 32) * 64;
    __shared__ float qs[32][65], ks[32][65];
    int tid = threadIdx.x;
    {
        int r = tid >> 3, c8 = (tid & 7) * 8;
        BF8 a; a.u4 = *reinterpret_cast<const uint4*>(qb + (size_t)r * 64 + c8);
        BF8 b; b.u4 = *reinterpret_cast<const uint4*>(kb + (size_t)r * 64 + c8);
        #pragma unroll
        for (int t = 0; t < 8; t++) { qs[r][c8 + t] = bf2f(a.h[t]); ks[r][c8 + t] = bf2f(b.h[t]); }
    }
    __syncthreads();
    int j = tid & 31, i4 = tid >> 5;
    float acc[4] = {0.f, 0.f, 0.f, 0.f};
    for (int d = 0; d < 64; d++) {
        float kv = ks[j][d];
        #pragma unroll
        for (int ii = 0; ii < 4; ii++) acc[ii] += qs[i4 * 4 + ii][d] * kv;
    }
    int boff = dir ? 31 : 95;
    float* so = (dir ? siml : simr) + ((size_t)(bh * p + g)) * 1024;
    float lmax = -1e30f;
    #pragma unroll
    for (int ii = 0; ii < 4; ii++) {
        int i = i4 * 4 + ii;
        float sv = acc[ii] + rpbl[((j - i) + boff) * 16 + h];
        so[i * 32 + j] = sv;
        lmax = fmaxf(lmax, sv);
    }
    for (int off = 32; off > 0; off >>= 1) lmax = fmaxf(lmax, __shfl_down(lmax, off));
    __shared__ float wm[4];
    if ((tid & 63) == 0) wm[tid >> 6] = lmax;
    __syncthreads();
    if (tid == 0) {
        float m2 = fmaxf(fmaxf(wm[0], wm[1]), fmaxf(wm[2], wm[3]));
        atomicMax(&m_enc[bh], encf(m2));
    }
}

__global__ void maxfin_kernel(const unsigned* __restrict__ me, float* __restrict__ mv)
{
    int i = threadIdx.x;
    if (i < 64) mv[i] = 3.0f * decf(me[i]);
}

// ---------------- coarse PV per level: yc[cr][d], zc[cr] (no full-res RMW) ----------------
__global__ __launch_bounds__(256) void pvc_kernel(
    const float* __restrict__ simr, const float* __restrict__ siml,
    const bfu* __restrict__ vc, const float* __restrict__ mval,
    float* __restrict__ yc, float* __restrict__ zc, int p, int rows)
{
    int bid = blockIdx.x;
    int g2 = bid % (2 * p); int bh = bid / (2 * p);
    int dir = g2 & 1, g = g2 >> 1;
    float m = mval[bh];
    const float* sp = (dir ? siml : simr) + ((size_t)(bh * p + g)) * 1024;
    __shared__ float ps[32][33];
    __shared__ float vs[32][65];
    int tid = threadIdx.x;
    {
        float4 s4 = reinterpret_cast<const float4*>(sp)[tid];
        int r = tid >> 3, c4 = (tid & 7) * 4;
        ps[r][c4 + 0] = expf(s4.x - m); ps[r][c4 + 1] = expf(s4.y - m);
        ps[r][c4 + 2] = expf(s4.z - m); ps[r][c4 + 3] = expf(s4.w - m);
    }
    const bfu* vb = vc + ((size_t)bh * rows + g * 64 + (1 - dir) * 32) * 64;
    {
        int r = tid >> 3, c8 = (tid & 7) * 8;
        BF8 a; a.u4 = *reinterpret_cast<const uint4*>(vb + (size_t)r * 64 + c8);
        #pragma unroll
        for (int t = 0; t < 8; t++) vs[r][c8 + t] = bf2f(a.h[t]);
    }
    __syncthreads();
    if (tid < 32) {
        float zs = 0.f;
        #pragma unroll
        for (int jj = 0; jj < 32; jj++) zs += ps[tid][jj];
        int cr = g * 64 + dir * 32 + tid;
        zc[(size_t)bh * rows + cr] = zs;
    }
    int d = tid & 63, i0 = tid >> 6;
    #pragma unroll
    for (int ii = 0; ii < 8; ii++) {
        int i = ii * 4 + i0;
        float a = 0.f;
        #pragma unroll
        for (int jj = 0; jj < 32; jj++) a += ps[i][jj] * vs[jj][d];
        int cr = g * 64 + dir * 32 + i;
        yc[((size_t)bh * rows + cr) * 64 + d] = a;
    }
}

// ---------------- fused: level-0 PV + coarse gather + normalize -> bf16 A ----------------
__global__ __launch_bounds__(256) void gather_kernel(
    const float* __restrict__ sim0, const bfu* __restrict__ v,
    const float* __restrict__ mval,
    const float* __restrict__ yc1, const float* __restrict__ ycB,
    const float* __restrict__ zcb, bfu* __restrict__ yA)
{
    int bid = blockIdx.x;
    int blk = bid & 127, bh = bid >> 7;
    float m = mval[bh];
    __shared__ float ps[32][33];
    __shared__ float vs[32][65];
    __shared__ float ycL[32][64];
    __shared__ float zcL[32];
    __shared__ float zrow[32];
    int tid = threadIdx.x;
    {
        float4 s4 = reinterpret_cast<const float4*>(sim0 + (size_t)bid * 1024)[tid];
        int r = tid >> 3, c4 = (tid & 7) * 4;
        ps[r][c4 + 0] = expf(s4.x - m); ps[r][c4 + 1] = expf(s4.y - m);
        ps[r][c4 + 2] = expf(s4.z - m); ps[r][c4 + 3] = expf(s4.w - m);
    }
    {
        const bfu* vb = v + ((size_t)bh * SS + blk * 32) * 64;
        int r = tid >> 3, c8 = (tid & 7) * 8;
        BF8 a; a.u4 = *reinterpret_cast<const uint4*>(vb + (size_t)r * 64 + c8);
        #pragma unroll
        for (int t = 0; t < 8; t++) vs[r][c8 + t] = bf2f(a.h[t]);
    }
    // stage coarse rows for all 6 levels
    const float* ybase[6];
    ybase[0] = yc1 + (size_t)bh * 2048 * 64;
    ybase[1] = ycB + 0       + (size_t)bh * 1024 * 64;
    ybase[2] = ycB + 4194304 + (size_t)bh * 512 * 64;
    ybase[3] = ycB + 6291456 + (size_t)bh * 256 * 64;
    ybase[4] = ycB + 7340032 + (size_t)bh * 128 * 64;
    ybase[5] = ycB + 7864320 + (size_t)bh * 64 * 64;
    const float* zbase[6];
    zbase[0] = zcb + 0      + (size_t)bh * 2048;
    zbase[1] = zcb + 131072 + (size_t)bh * 1024;
    zbase[2] = zcb + 196608 + (size_t)bh * 512;
    zbase[3] = zcb + 229376 + (size_t)bh * 256;
    zbase[4] = zcb + 245760 + (size_t)bh * 128;
    zbase[5] = zcb + 253952 + (size_t)bh * 64;
    const int Pl[6] = {0, 16, 24, 28, 30, 31};
    const int nl[6] = {16, 8, 4, 2, 1, 1};
    #pragma unroll
    for (int l = 1; l <= 6; l++) {
        int base_cr = (blk * 32) >> l;
        int cnt = nl[l - 1] * 64;
        for (int idx = tid; idx < cnt; idx += 256) {
            int rr = idx >> 6, dd = idx & 63;
            ycL[Pl[l - 1] + rr][dd] = ybase[l - 1][(size_t)(base_cr + rr) * 64 + dd];
        }
        if (tid < nl[l - 1]) zcL[Pl[l - 1] + tid] = zbase[l - 1][base_cr + tid];
    }
    __syncthreads();
    if (tid < 32) {
        float zs = 0.f;
        #pragma unroll
        for (int jj = 0; jj < 32; jj++) zs += ps[tid][jj];
        #pragma unroll
        for (int l = 1; l <= 6; l++) zs += zcL[Pl[l - 1] + (tid >> l)];
        zrow[tid] = 1.0f / zs;
    }
    __syncthreads();
    int d = tid & 63, i0 = tid >> 6;
    int b = bh >> 4, h = bh & 15, s0 = blk * 32;
    #pragma unroll
    for (int ii = 0; ii < 8; ii++) {
        int i = ii * 4 + i0;
        float a = 0.f;
        #pragma unroll
        for (int jj = 0; jj < 32; jj++) a += ps[i][jj] * vs[jj][d];
        #pragma unroll
        for (int l = 1; l <= 6; l++) a += ycL[Pl[l - 1] + (i >> l)][d];
        a *= zrow[i];
        yA[((size_t)(b * SS + s0 + i)) * 1024 + h * 64 + d] = f2bf(a);
    }
}

extern "C" void kernel_launch(void* const* d_in, const int* in_sizes, int n_in,
                              void* d_out, int out_size, void* d_ws, size_t ws_size,
                              hipStream_t stream)
{
    const float* x   = (const float*)d_in[0];
    const float* wq  = (const float*)d_in[1];
    const float* bq  = (const float*)d_in[2];
    const float* wk  = (const float*)d_in[3];
    const float* bk  = (const float*)d_in[4];
    const float* wv  = (const float*)d_in[5];
    const float* bv  = (const float*)d_in[6];
    const float* rpb = (const float*)d_in[7];
    const float* wo  = (const float*)d_in[8];
    const float* bo  = (const float*)d_in[9];
    float* out = (float*)d_out;

    const size_t NEED = 267387392ULL;   // 255.0 MiB
    if (ws_size < NEED) {
        float val = (float)(ws_size >> 20);
        int n = out_size;
        hipLaunchKernelGGL(diag_kernel, dim3((n + 255) / 256), dim3(256), 0, stream, out, val, n);
        return;
    }

    char* w8 = (char*)d_ws;
    bfu* q    = (bfu*)(w8);                       // 33,554,432 B ; reused as yA after sim0
    bfu* k    = (bfu*)(w8 + 33554432);            // reused as ycb level-1 after sim0
    bfu* v    = (bfu*)(w8 + 67108864);
    bfu* qc   = (bfu*)(w8 + 100663296);           // 33,030,144 B ; reused as ycb levels 2-6 after simL
    bfu* kc   = (bfu*)(w8 + 133693440);           // reused as zcb + wot after simL
    bfu* vc   = (bfu*)(w8 + 166723584);
    float* sim0 = (float*)(w8 + 199753728);       // 33,554,432 B
    float* simr = (float*)(w8 + 233308160);       // 16,515,072 B
    float* siml = (float*)(w8 + 249823232);       // 16,515,072 B
    unsigned* m_enc = (unsigned*)(w8 + 267386880);
    float* m_val    = (float*)(w8 + 267387136);
    // transient aliases (lifetimes disjoint, stream-ordered):
    bfu* xbf    = (bfu*)sim0;                     // stages 1-2 (sim0 written later)
    bfu* wqkv_t = (bfu*)simr;                     // stages 1-2 (simr written later)
    float* yc1  = (float*)k;                      // after sim0: k dead
    float* ycB  = (float*)qc;                     // after simL: qc dead
    float* zcb  = (float*)kc;                     // after simL: kc dead (first 1.1 MB)
    bfu* wot    = (bfu*)(w8 + 133693440 + 2097152); // kc slot +2MB (disjoint from zcb)
    bfu* yA     = q;                              // after sim0: q dead

    // 1. bf16 conversions: x, transposed weights [N][K]
    hipLaunchKernelGGL(f32_to_bf16_kernel, dim3(8192), dim3(256), 0, stream, x, xbf, 2097152);
    hipLaunchKernelGGL(transpose_w_kernel, dim3(32, 32), dim3(256), 0, stream, wq, wqkv_t);
    hipLaunchKernelGGL(transpose_w_kernel, dim3(32, 32), dim3(256), 0, stream, wk, wqkv_t + 1048576);
    hipLaunchKernelGGL(transpose_w_kernel, dim3(32, 32), dim3(256), 0, stream, wv, wqkv_t + 2097152);

    // 2. QKV projection (bf16 MFMA)
    hipLaunchKernelGGL(gemm_qkv_mfma, dim3(24, 128), dim3(256), 0, stream,
                       xbf, wqkv_t, bq, bk, bv, q, k, v);

    // 3. coarsen pyramid — single launch, all levels
    hipLaunchKernelGGL(coarsen_all_kernel, dim3(12288), dim3(256), 0, stream, q, k, v, qc, kc, vc);

    // 4. similarities + global max
    hipMemsetAsync(m_enc, 0, 64 * sizeof(unsigned), stream);
    hipLaunchKernelGGL(sim0_kernel, dim3(8192), dim3(256), 0, stream, q, k, rpb, sim0, m_enc);
    static const size_t GOFF[7] = {0, 0, 8388608, 12582912, 14680064, 15728640, 16252928};
    static const size_t SOFF[7] = {0, 0, 2097152, 3145728, 3670016, 3932160, 4063232};
    for (int l = 1; l <= 6; l++) {
        int p = 64 >> l, rows = SS >> l;
        hipLaunchKernelGGL(simL_kernel, dim3(BH * p * 2), dim3(256), 0, stream,
                           qc + GOFF[l], kc + GOFF[l], rpb + (size_t)l * 127 * 16,
                           simr + SOFF[l], siml + SOFF[l], m_enc, p, rows);
    }
    hipLaunchKernelGGL(maxfin_kernel, dim3(1), dim3(64), 0, stream, m_enc, m_val);

    // 5. coarse PV per level (writes ycb/zcb over dead k/qc/kc slots)
    float* ycp[7]; float* zcp[7];
    ycp[1] = yc1;            zcp[1] = zcb;
    ycp[2] = ycB;            zcp[2] = zcb + 131072;
    ycp[3] = ycB + 4194304;  zcp[3] = zcb + 196608;
    ycp[4] = ycB + 6291456;  zcp[4] = zcb + 229376;
    ycp[5] = ycB + 7340032;  zcp[5] = zcb + 245760;
    ycp[6] = ycB + 7864320;  zcp[6] = zcb + 253952;
    for (int l = 1; l <= 6; l++) {
        int p = 64 >> l, rows = SS >> l;
        hipLaunchKernelGGL(pvc_kernel, dim3(BH * p * 2), dim3(256), 0, stream,
                           simr + SOFF[l], siml + SOFF[l], vc + GOFF[l], m_val,
                           ycp[l], zcp[l], p, rows);
    }

    // 6. transpose Wo (kc slot dead past simL; disjoint from zcb)
    hipLaunchKernelGGL(transpose_w_kernel, dim3(32, 32), dim3(256), 0, stream, wo, wot);

    // 7. fused level-0 PV + gather + normalize -> bf16 A (over dead q slot)
    hipLaunchKernelGGL(gather_kernel, dim3(8192), dim3(256), 0, stream,
                       sim0, v, m_val, yc1, ycB, zcb, yA);

    // 8. output projection (bf16 MFMA)
    hipLaunchKernelGGL(gemm_out_mfma, dim3(8, 128), dim3(256), 0, stream, yA, wot, bo, out);
}